// Round 1
// baseline (376.252 us; speedup 1.0000x reference)
//
#include <hip/hip_runtime.h>

#define NB 8
#define NPTS 16384
#define NCEN 2048
#define NCH 256
#define KMAX 64
#define NROWCH (NCH + 3)  // 259 output channels

// Kernel 1: ball-query "last in-radius index" per (batch, centroid).
// 512 blocks x 512 threads: block = (batch b, 32 centroids); each centroid is
// covered by 16 threads, each scanning a 1024-point chunk; LDS max-reduce.
// Lanes 0..31 of a wave share the same point address (HW broadcast).
__global__ __launch_bounds__(512) void ball_query_kernel(
    const float* __restrict__ pts, const float* __restrict__ cent,
    int* __restrict__ idx_out) {
#pragma clang fp contract(off)
  const int blk = blockIdx.x;        // 512 blocks: 8 batches * 64 groups of 32
  const int b = blk >> 6;
  const int j0 = (blk & 63) * 32;
  const int t = threadIdx.x;
  const int c = t & 31;              // centroid within group
  const int chunk = t >> 5;          // 0..15 point chunk
  const int j = j0 + c;
  const float* cp = cent + ((size_t)b * NCEN + j) * 3;
  const float cx = cp[0], cy = cp[1], cz = cp[2];
  const float rad2 = (float)(0.4 * 0.4);   // match python RADIUS*RADIUS -> f32
  const float* pb = pts + (size_t)b * NPTS * 3;
  const int k0 = chunk * (NPTS / 16);
  int last = -1;
#pragma unroll 4
  for (int k = k0; k < k0 + NPTS / 16; ++k) {
    const float px = pb[k * 3 + 0];
    const float py = pb[k * 3 + 1];
    const float pz = pb[k * 3 + 2];
    const float dx = cx - px, dy = cy - py, dz = cz - pz;
    float d2 = dx * dx + dy * dy;     // numpy order: (dx^2 + dy^2) + dz^2,
    d2 = d2 + dz * dz;                // no fma contraction (pragma above)
    if (d2 < rad2) last = k;          // ascending k -> keeps LAST in-radius
  }
  __shared__ int red[16][32];
  red[chunk][c] = last;
  __syncthreads();
  if (t < 32) {
    int m = red[0][t];
#pragma unroll
    for (int q = 1; q < 16; ++q) m = max(m, red[q][t]);
    idx_out[b * NCEN + j0 + t] = max(m, 0);  // -1 (no hit) -> 0
  }
}

// Kernel 2: fill output (B, 259, Np, K). One thread per output float4;
// g is exactly the float4 index -> perfectly coalesced 1KB/wave stores.
// 16 lanes share one (b,ch,j) row -> broadcast idx/feature gathers.
__global__ __launch_bounds__(256) void group_kernel(
    const float* __restrict__ pts, const float* __restrict__ cent,
    const float* __restrict__ feat, const int* __restrict__ idx,
    float4* __restrict__ out) {
  const unsigned g = blockIdx.x * 256u + threadIdx.x;
  const unsigned row = g >> 4;                 // (b, ch, j), K/4 = 16 per row
  const unsigned b = row / (NROWCH * NCEN);
  const unsigned rem = row % (NROWCH * NCEN);
  const unsigned ch = rem >> 11;               // / NCEN
  const unsigned j = rem & (NCEN - 1);
  const int id = idx[b * NCEN + j];
  float v;
  if (ch < 3) {
    const float p = pts[((size_t)b * NPTS + id) * 3 + ch];
    const float cc = cent[((size_t)b * NCEN + j) * 3 + ch];
    v = (p - cc) / 0.4f;                       // exact-division, matches ref
  } else {
    v = feat[((size_t)b * NCH + (ch - 3)) * NPTS + id];
  }
  out[g] = make_float4(v, v, v, v);
}

extern "C" void kernel_launch(void* const* d_in, const int* in_sizes, int n_in,
                              void* d_out, int out_size, void* d_ws, size_t ws_size,
                              hipStream_t stream) {
  const float* pts = (const float*)d_in[0];   // (8,16384,3) f32
  const float* cent = (const float*)d_in[1];  // (8,2048,3)  f32
  const float* feat = (const float*)d_in[2];  // (8,256,16384) f32
  int* idx = (int*)d_ws;                      // 8*2048 int32 = 64 KB scratch
  float4* out = (float4*)d_out;               // (8,259,2048,64) f32

  ball_query_kernel<<<512, 512, 0, stream>>>(pts, cent, idx);

  const unsigned total4 = (unsigned)NB * NROWCH * NCEN * KMAX / 4;  // 67,895,296
  group_kernel<<<total4 / 256u, 256, 0, stream>>>(pts, cent, feat, idx, out);
}

// Round 3
// 181.080 us; speedup vs baseline: 2.0778x; 2.0778x over previous
//
#include <hip/hip_runtime.h>

#define NB 8
#define NPTS 16384
#define NCEN 2048
#define NCH 256
#define KMAX 64
#define NROWCH (NCH + 3)  // 259 output channels

typedef float f32x4 __attribute__((ext_vector_type(4)));  // native vec for nontemporal builtin

// Kernel 1: ball-query "last in-radius index" = FIRST hit scanning k downward.
// One thread per (batch, centroid): 16384 threads. All 64 lanes of a wave share
// one batch (2048 % 64 == 0) and the same k -> point loads are wave-uniform
// (scalar-cache friendly). Early exit when every lane in the wave has found its
// hit: expected ~30-300 iterations instead of 16384.
// Per-pair float arithmetic is IDENTICAL to the verified exact-order formula
// ((dx^2+dy^2)+dz^2, no fma) -> selection bit-exact vs numpy.
__global__ __launch_bounds__(256) void ball_query_kernel(
    const float* __restrict__ pts, const float* __restrict__ cent,
    int* __restrict__ idx_out) {
#pragma clang fp contract(off)
  const int g = blockIdx.x * 256 + threadIdx.x;  // 0..16383
  const int b = g >> 11;                         // / NCEN
  const int j = g & (NCEN - 1);
  const float* cp = cent + ((size_t)b * NCEN + j) * 3;
  const float cx = cp[0], cy = cp[1], cz = cp[2];
  const float rad2 = (float)(0.4 * 0.4);
  const float* pb = pts + (size_t)b * NPTS * 3;
  int res = -1;
  bool found = false;
  // unroll-by-4 groups, descending; within a group process k+3..k in order
  // with the !found guard so only the LARGEST in-radius k is recorded.
  for (int k = NPTS - 4; k >= 0; k -= 4) {
    const float x3 = pb[(k + 3) * 3 + 0], y3 = pb[(k + 3) * 3 + 1], z3 = pb[(k + 3) * 3 + 2];
    const float x2 = pb[(k + 2) * 3 + 0], y2 = pb[(k + 2) * 3 + 1], z2 = pb[(k + 2) * 3 + 2];
    const float x1 = pb[(k + 1) * 3 + 0], y1 = pb[(k + 1) * 3 + 1], z1 = pb[(k + 1) * 3 + 2];
    const float x0 = pb[(k + 0) * 3 + 0], y0 = pb[(k + 0) * 3 + 1], z0 = pb[(k + 0) * 3 + 2];
    {
      const float dx = cx - x3, dy = cy - y3, dz = cz - z3;
      float d2 = dx * dx + dy * dy; d2 = d2 + dz * dz;
      if (!found && d2 < rad2) { res = k + 3; found = true; }
    }
    {
      const float dx = cx - x2, dy = cy - y2, dz = cz - z2;
      float d2 = dx * dx + dy * dy; d2 = d2 + dz * dz;
      if (!found && d2 < rad2) { res = k + 2; found = true; }
    }
    {
      const float dx = cx - x1, dy = cy - y1, dz = cz - z1;
      float d2 = dx * dx + dy * dy; d2 = d2 + dz * dz;
      if (!found && d2 < rad2) { res = k + 1; found = true; }
    }
    {
      const float dx = cx - x0, dy = cy - y0, dz = cz - z0;
      float d2 = dx * dx + dy * dy; d2 = d2 + dz * dz;
      if (!found && d2 < rad2) { res = k; found = true; }
    }
    if (__all(found)) break;
  }
  idx_out[g] = res < 0 ? 0 : res;
}

// Kernel 2: fill output (B, 259, Np, K). One thread per output float4 ->
// wave writes 1 KB contiguous. 16 rows per block, (b,ch) uniform per block
// (2048/16=128 blocks per channel, never straddles), decoded scalar.
// XCD-chunked bijective swizzle keeps each 64KB feature row's 128 gathering
// blocks on ONE XCD's L2; nontemporal stores keep the 1.09 GB write stream
// from evicting the gather working set.
__global__ __launch_bounds__(256) void group_kernel(
    const float* __restrict__ pts, const float* __restrict__ cent,
    const float* __restrict__ feat, const int* __restrict__ idx,
    f32x4* __restrict__ out) {
  const unsigned nblk = gridDim.x;        // 265216, divisible by 8
  const unsigned cpx = nblk >> 3;         // blocks per XCD chunk
  const unsigned bid = blockIdx.x;
  const unsigned blk = (bid & 7) * cpx + (bid >> 3);  // bijective XCD swizzle

  const unsigned row0 = blk * 16;                   // first (b,ch,j) row
  const unsigned b = row0 / (NROWCH * NCEN);        // scalar (block-uniform)
  const unsigned rem = row0 % (NROWCH * NCEN);
  const unsigned ch = rem >> 11;                    // / NCEN, block-uniform
  const unsigned j0 = rem & (NCEN - 1);             // multiple of 16
  const unsigned t = threadIdx.x;
  const unsigned j = j0 + (t >> 4);                 // 16 lanes per row

  const int id = idx[b * NCEN + j];
  float v;
  if (ch < 3) {
    const float p = pts[((size_t)b * NPTS + id) * 3 + ch];
    const float cc = cent[((size_t)b * NCEN + j) * 3 + ch];
    v = (p - cc) / 0.4f;                            // exact division, matches ref
  } else {
    v = feat[((size_t)b * NCH + (ch - 3)) * NPTS + id];
  }
  f32x4 o; o.x = v; o.y = v; o.z = v; o.w = v;
  __builtin_nontemporal_store(o, out + (size_t)blk * 256 + t);
}

extern "C" void kernel_launch(void* const* d_in, const int* in_sizes, int n_in,
                              void* d_out, int out_size, void* d_ws, size_t ws_size,
                              hipStream_t stream) {
  const float* pts = (const float*)d_in[0];   // (8,16384,3) f32
  const float* cent = (const float*)d_in[1];  // (8,2048,3)  f32
  const float* feat = (const float*)d_in[2];  // (8,256,16384) f32
  int* idx = (int*)d_ws;                      // 8*2048 int32 = 64 KB scratch
  f32x4* out = (f32x4*)d_out;                 // (8,259,2048,64) f32

  ball_query_kernel<<<(NB * NCEN) / 256, 256, 0, stream>>>(pts, cent, idx);

  const unsigned total4 = (unsigned)NB * NROWCH * NCEN * KMAX / 4;  // 67,895,296
  group_kernel<<<total4 / 256u, 256, 0, stream>>>(pts, cent, feat, idx, out);
}